// Round 1
// baseline (258.248 us; speedup 1.0000x reference)
//
#include <hip/hip_runtime.h>

#define B_ 4
#define H_ 4
#define N_ 2048
#define D_ 128
#define HD_ 64

typedef __attribute__((ext_vector_type(8))) __bf16 bf16x8;
typedef __attribute__((ext_vector_type(8))) unsigned short u16x8;
typedef __attribute__((ext_vector_type(4))) float f32x4;

__device__ inline unsigned short f2bf(float f) {
  unsigned u = __builtin_bit_cast(unsigned, f);
  u += 0x7FFFu + ((u >> 16) & 1u);   // RNE
  return (unsigned short)(u >> 16);
}

__device__ inline f32x4 mfma_bf16(u16x8 a, u16x8 b, f32x4 c) {
  return __builtin_amdgcn_mfma_f32_16x16x32_bf16(
      __builtin_bit_cast(bf16x8, a), __builtin_bit_cast(bf16x8, b), c, 0, 0, 0);
}

// ---------------- prep: pack weights to bf16 ----------------
// Wc1[h][r][k] (128x128): r<64 -> w0[h][r][k]; r>=64 -> w1[h][r-64][k] (first 128 of K)
// Wc2[h][r][k] (64x64):   w1[h][r][128+k]
// Wcat[d][c] (128x640): c<256 -> Wf[d][h*128+j]; 256..511 -> Wf[d][h*128+64+j]; 512.. -> sum_h Wf[d][h*128+k]
__global__ __launch_bounds__(256) void prep_weights(
    const float* __restrict__ w0, const float* __restrict__ w1,
    const float* __restrict__ Wf,
    unsigned short* __restrict__ Wc1, unsigned short* __restrict__ Wc2,
    unsigned short* __restrict__ Wcat)
{
  int idx = blockIdx.x * 256 + threadIdx.x;
  if (idx < 65536) {
    int h = idx >> 14, r = (idx >> 7) & 127, k = idx & 127;
    float v = (r < 64) ? w0[(h * 64 + r) * 128 + k]
                       : w1[(h * 64 + (r - 64)) * 192 + k];
    Wc1[idx] = f2bf(v);
  } else if (idx < 81920) {
    int i = idx - 65536;
    int h = i >> 12, r = (i >> 6) & 63, k = i & 63;
    Wc2[i] = f2bf(w1[(h * 64 + r) * 192 + 128 + k]);
  } else if (idx < 163840) {
    int i = idx - 81920;
    int d = i / 640, c = i % 640;
    float v;
    if (c < 256)      { int h = c >> 6, j = c & 63;        v = Wf[d * 512 + h * 128 + j]; }
    else if (c < 512) { int h = (c - 256) >> 6, j = (c - 256) & 63; v = Wf[d * 512 + h * 128 + 64 + j]; }
    else {
      int k = c - 512; v = 0.f;
      for (int hh = 0; hh < 4; ++hh) v += Wf[d * 512 + hh * 128 + k];
    }
    Wcat[i] = f2bf(v);
  }
}

// ---------------- prep: X -> XbT (bf16 transpose, [B][128][N]) + G X-slice ----------------
__global__ __launch_bounds__(256) void prep_x(
    const float* __restrict__ X, unsigned short* __restrict__ XbT,
    unsigned short* __restrict__ G)
{
  const int tid = threadIdx.x;
  const int b = blockIdx.x >> 5;
  const int n0 = (blockIdx.x & 31) * 64;
  __shared__ float tf[64][129];
  #pragma unroll
  for (int i = 0; i < 32; ++i) {
    int e = i * 256 + tid;          // 0..8191 over 64x128
    int nl = e >> 7, c = e & 127;
    float v = X[((size_t)b * N_ + n0 + nl) * 128 + c];
    tf[nl][c] = v;
    G[((size_t)b * N_ + n0 + nl) * 640 + 512 + c] = f2bf(v);
  }
  __syncthreads();
  #pragma unroll
  for (int i = 0; i < 32; ++i) {
    int e = i * 256 + tid;
    int c = e >> 6, nl = e & 63;
    XbT[((size_t)b * 128 + c) * N_ + n0 + nl] = f2bf(tf[nl][c]);
  }
}

// ---------------- pass1: Y0 = adj @ X  -> Z0 = Y0 + X, denom ----------------
__global__ __launch_bounds__(256) void pass1_kernel(
    const float* __restrict__ adj, const float* __restrict__ X,
    const unsigned short* __restrict__ XbT,
    float* __restrict__ Z0, float* __restrict__ dnm)
{
  const int tid = threadIdx.x;
  const int lane = tid & 63;
  const int w = tid >> 6;
  const int r_lo = lane & 15;
  const int q = lane >> 4;
  const int bh = blockIdx.y;          // b*4 + h
  const int b = bh >> 2, h = bh & 3;
  const int hb = h * 4 + b;
  const int row0 = blockIdx.x * 128;

  __shared__ unsigned short At[2][128][40];
  __shared__ unsigned short Bt[2][128][40];
  __shared__ float rowpart[256];

  const int arow = tid >> 1;
  const int ahalf = tid & 1;
  const float* aRow = adj + ((size_t)bh * N_ + (row0 + arow)) * N_ + ahalf * 16;
  const unsigned short* xb = XbT + (size_t)b * 128 * N_;
  const int bc = tid >> 2, bq = tid & 3;

  f32x4 acc[2][8] = {};
  float rsum = 0.f;
  float4 ar0, ar1, ar2, ar3;
  uint4 br0, br1;

  auto issue = [&](int t) {
    const float4* p = (const float4*)(aRow + (size_t)t * 32);
    ar0 = p[0]; ar1 = p[1]; ar2 = p[2]; ar3 = p[3];
    const unsigned short* xp = xb + (size_t)t * 32;
    br0 = *(const uint4*)(xp + (size_t)bc * N_ + bq * 8);
    br1 = *(const uint4*)(xp + (size_t)(bc + 64) * N_ + bq * 8);
  };
  auto cvt_write = [&](int buf) {
    float f[16] = {ar0.x, ar0.y, ar0.z, ar0.w, ar1.x, ar1.y, ar1.z, ar1.w,
                   ar2.x, ar2.y, ar2.z, ar2.w, ar3.x, ar3.y, ar3.z, ar3.w};
    u16x8 v0, v1;
    #pragma unroll
    for (int i = 0; i < 8; ++i) {
      rsum += f[i] + f[i + 8];
      v0[i] = f2bf(f[i]); v1[i] = f2bf(f[i + 8]);
    }
    *(u16x8*)&At[buf][arow][ahalf * 16] = v0;
    *(u16x8*)&At[buf][arow][ahalf * 16 + 8] = v1;
    *(uint4*)&Bt[buf][bc][bq * 8] = br0;
    *(uint4*)&Bt[buf][bc + 64][bq * 8] = br1;
  };
  auto compute = [&](int buf) {
    u16x8 a0 = *(u16x8*)&At[buf][w * 32 + r_lo][q * 8];
    u16x8 a1 = *(u16x8*)&At[buf][w * 32 + 16 + r_lo][q * 8];
    #pragma unroll
    for (int ct = 0; ct < 8; ++ct) {
      u16x8 bF = *(u16x8*)&Bt[buf][ct * 16 + r_lo][q * 8];
      acc[0][ct] = mfma_bf16(a0, bF, acc[0][ct]);
      acc[1][ct] = mfma_bf16(a1, bF, acc[1][ct]);
    }
  };

  issue(0);
  cvt_write(0);
  __syncthreads();
  for (int t = 0; t < 64; ++t) {
    const int buf = t & 1;
    if (t < 63) issue(t + 1);
    compute(buf);
    if (t < 63) cvt_write(buf ^ 1);
    __syncthreads();
  }

  rowpart[tid] = rsum;
  __syncthreads();

  #pragma unroll
  for (int rt = 0; rt < 2; ++rt) {
    #pragma unroll
    for (int j = 0; j < 4; ++j) {
      const int rl = w * 32 + rt * 16 + q * 4 + j;
      const int n = row0 + rl;
      const float den = rowpart[2 * rl] + rowpart[2 * rl + 1] + 1.0f;
      if (r_lo == 0) dnm[(size_t)hb * N_ + n] = den;
      const float* xrow = X + ((size_t)b * N_ + n) * 128;
      float* zrow = Z0 + ((size_t)hb * N_ + n) * 128;
      #pragma unroll
      for (int ct = 0; ct < 8; ++ct) {
        const int c = ct * 16 + r_lo;
        zrow[c] = acc[rt][ct][j] + xrow[c];
      }
    }
  }
}

// ---------------- mid: g0, h0 = g0@w1b^T, e = Z0@w1a^T + h0 + 2*b1 ----------------
__global__ __launch_bounds__(256) void mid_kernel(
    const float* __restrict__ Z0, const float* __restrict__ dnm,
    const unsigned short* __restrict__ Wc1, const unsigned short* __restrict__ Wc2,
    const float* __restrict__ bias0, const float* __restrict__ bias1,
    float* __restrict__ e_buf, unsigned short* __restrict__ h0T,
    unsigned short* __restrict__ G)
{
  const int tid = threadIdx.x;
  const int lane = tid & 63;
  const int w = tid >> 6;
  const int r_lo = lane & 15;
  const int q = lane >> 4;
  const int h = blockIdx.y;
  const int rowbase = blockIdx.x * 128;     // over B*N = 8192
  const int bb = rowbase >> 11;
  const int n0 = rowbase & 2047;

  __shared__ unsigned short g0L[128][72];
  __shared__ unsigned short h0L[64][136];
  __shared__ float denL[128];

  if (tid < 128) denL[tid] = dnm[(size_t)h * 8192 + rowbase + tid];

  const float* zbase = Z0 + (size_t)(h * 8192 + rowbase) * 128;

  f32x4 acc1[2][8] = {};
  #pragma unroll
  for (int ks = 0; ks < 4; ++ks) {
    u16x8 aF[2];
    #pragma unroll
    for (int rt = 0; rt < 2; ++rt) {
      const float* p = zbase + (size_t)(w * 32 + rt * 16 + r_lo) * 128 + ks * 32 + q * 8;
      float4 f0 = *(const float4*)p;
      float4 f1 = *(const float4*)(p + 4);
      u16x8 v;
      v[0] = f2bf(f0.x); v[1] = f2bf(f0.y); v[2] = f2bf(f0.z); v[3] = f2bf(f0.w);
      v[4] = f2bf(f1.x); v[5] = f2bf(f1.y); v[6] = f2bf(f1.z); v[7] = f2bf(f1.w);
      aF[rt] = v;
    }
    #pragma unroll
    for (int ct = 0; ct < 8; ++ct) {
      u16x8 bF = *(const u16x8*)(Wc1 + ((size_t)h * 128 + ct * 16 + r_lo) * 128 + ks * 32 + q * 8);
      acc1[0][ct] = mfma_bf16(aF[0], bF, acc1[0][ct]);
      acc1[1][ct] = mfma_bf16(aF[1], bF, acc1[1][ct]);
    }
  }
  __syncthreads();   // denL ready

  // epilogue 1: g0 = relu((t0 + 2 b0)/den)
  #pragma unroll
  for (int rt = 0; rt < 2; ++rt) {
    #pragma unroll
    for (int j = 0; j < 4; ++j) {
      const int rl = w * 32 + rt * 16 + q * 4 + j;
      const float den = denL[rl];
      const size_t grow = (size_t)(rowbase + rl);
      #pragma unroll
      for (int ct = 0; ct < 4; ++ct) {
        const int c = ct * 16 + r_lo;
        float g = (acc1[rt][ct][j] + 2.f * bias0[h * 64 + c]) / den;
        g = fmaxf(g, 0.f);
        unsigned short gb = f2bf(g);
        g0L[rl][c] = gb;
        G[grow * 640 + h * 64 + c] = gb;
      }
    }
  }
  __syncthreads();

  // GEMM2: h0 = g0 @ w1b^T
  f32x4 acc2[2][4] = {};
  #pragma unroll
  for (int ks = 0; ks < 2; ++ks) {
    u16x8 aF[2];
    #pragma unroll
    for (int rt = 0; rt < 2; ++rt)
      aF[rt] = *(u16x8*)&g0L[w * 32 + rt * 16 + r_lo][ks * 32 + q * 8];
    #pragma unroll
    for (int ct = 0; ct < 4; ++ct) {
      u16x8 bF = *(const u16x8*)(Wc2 + ((size_t)h * 64 + ct * 16 + r_lo) * 64 + ks * 32 + q * 8);
      acc2[0][ct] = mfma_bf16(aF[0], bF, acc2[0][ct]);
      acc2[1][ct] = mfma_bf16(aF[1], bF, acc2[1][ct]);
    }
  }

  // epilogue 2: e = s + h0 + 2 b1 ; h0 -> transposed LDS
  #pragma unroll
  for (int rt = 0; rt < 2; ++rt) {
    #pragma unroll
    for (int j = 0; j < 4; ++j) {
      const int rl = w * 32 + rt * 16 + q * 4 + j;
      #pragma unroll
      for (int ct = 0; ct < 4; ++ct) {
        const int c = ct * 16 + r_lo;
        float h0v = acc2[rt][ct][j];
        float ev = acc1[rt][4 + ct][j] + h0v + 2.f * bias1[h * 64 + c];
        e_buf[(size_t)(h * 8192 + rowbase + rl) * 64 + c] = ev;
        h0L[c][rl] = f2bf(h0v);
      }
    }
  }
  __syncthreads();

  // write h0T [H][B][64][N] coalesced
  {
    const int c = tid >> 2;
    const int qq = tid & 3;
    unsigned short* dst = h0T + ((size_t)(h * 4 + bb) * 64 + c) * N_ + n0 + qq * 32;
    const unsigned short* src = &h0L[c][qq * 32];
    #pragma unroll
    for (int i = 0; i < 4; ++i)
      *(uint4*)(dst + i * 8) = *(const uint4*)(src + i * 8);
  }
}

// ---------------- pass2: V = adj @ h0 -> g1 = relu((V + e)/den) ----------------
__global__ __launch_bounds__(256) void pass2_kernel(
    const float* __restrict__ adj, const unsigned short* __restrict__ h0T,
    const float* __restrict__ e_buf, const float* __restrict__ dnm,
    unsigned short* __restrict__ G)
{
  const int tid = threadIdx.x;
  const int lane = tid & 63;
  const int w = tid >> 6;
  const int r_lo = lane & 15;
  const int q = lane >> 4;
  const int bh = blockIdx.y;
  const int b = bh >> 2, h = bh & 3;
  const int hb = h * 4 + b;
  const int row0 = blockIdx.x * 128;

  __shared__ unsigned short At[2][128][40];
  __shared__ unsigned short Bt[2][64][40];

  const int arow = tid >> 1;
  const int ahalf = tid & 1;
  const float* aRow = adj + ((size_t)bh * N_ + (row0 + arow)) * N_ + ahalf * 16;
  const unsigned short* hbase = h0T + (size_t)hb * 64 * N_;
  const int bc = tid >> 2, bq = tid & 3;

  f32x4 acc[2][4] = {};
  float4 ar0, ar1, ar2, ar3;
  uint4 br0;

  auto issue = [&](int t) {
    const float4* p = (const float4*)(aRow + (size_t)t * 32);
    ar0 = p[0]; ar1 = p[1]; ar2 = p[2]; ar3 = p[3];
    br0 = *(const uint4*)(hbase + (size_t)bc * N_ + t * 32 + bq * 8);
  };
  auto cvt_write = [&](int buf) {
    float f[16] = {ar0.x, ar0.y, ar0.z, ar0.w, ar1.x, ar1.y, ar1.z, ar1.w,
                   ar2.x, ar2.y, ar2.z, ar2.w, ar3.x, ar3.y, ar3.z, ar3.w};
    u16x8 v0, v1;
    #pragma unroll
    for (int i = 0; i < 8; ++i) { v0[i] = f2bf(f[i]); v1[i] = f2bf(f[i + 8]); }
    *(u16x8*)&At[buf][arow][ahalf * 16] = v0;
    *(u16x8*)&At[buf][arow][ahalf * 16 + 8] = v1;
    *(uint4*)&Bt[buf][bc][bq * 8] = br0;
  };
  auto compute = [&](int buf) {
    u16x8 a0 = *(u16x8*)&At[buf][w * 32 + r_lo][q * 8];
    u16x8 a1 = *(u16x8*)&At[buf][w * 32 + 16 + r_lo][q * 8];
    #pragma unroll
    for (int ct = 0; ct < 4; ++ct) {
      u16x8 bF = *(u16x8*)&Bt[buf][ct * 16 + r_lo][q * 8];
      acc[0][ct] = mfma_bf16(a0, bF, acc[0][ct]);
      acc[1][ct] = mfma_bf16(a1, bF, acc[1][ct]);
    }
  };

  issue(0);
  cvt_write(0);
  __syncthreads();
  for (int t = 0; t < 64; ++t) {
    const int buf = t & 1;
    if (t < 63) issue(t + 1);
    compute(buf);
    if (t < 63) cvt_write(buf ^ 1);
    __syncthreads();
  }

  #pragma unroll
  for (int rt = 0; rt < 2; ++rt) {
    #pragma unroll
    for (int j = 0; j < 4; ++j) {
      const int rl = w * 32 + rt * 16 + q * 4 + j;
      const int n = row0 + rl;
      const float den = dnm[(size_t)hb * N_ + n];
      const float* er = e_buf + ((size_t)hb * N_ + n) * 64;
      unsigned short* gr = G + ((size_t)b * N_ + n) * 640 + 256 + h * 64;
      #pragma unroll
      for (int ct = 0; ct < 4; ++ct) {
        const int c = ct * 16 + r_lo;
        float v = (acc[rt][ct][j] + er[c]) / den;
        gr[c] = f2bf(fmaxf(v, 0.f));
      }
    }
  }
}

// ---------------- pass3: out = G @ Wcat^T + bf ----------------
__global__ __launch_bounds__(256) void pass3_kernel(
    const unsigned short* __restrict__ G, const unsigned short* __restrict__ Wcat,
    const float* __restrict__ bfv, float* __restrict__ out)
{
  const int tid = threadIdx.x;
  const int lane = tid & 63;
  const int w = tid >> 6;
  const int r_lo = lane & 15;
  const int q = lane >> 4;
  const int row0 = blockIdx.x * 128;    // over B*N = 8192

  __shared__ unsigned short At[2][128][40];

  const int arow = tid >> 1;
  const int aq = (tid & 1) * 2;
  const unsigned short* gRow = G + (size_t)(row0 + arow) * 640 + aq * 8;

  f32x4 acc[2][8] = {};
  uint4 g0r, g1r;

  auto issue = [&](int t) {
    g0r = *(const uint4*)(gRow + (size_t)t * 32);
    g1r = *(const uint4*)(gRow + (size_t)t * 32 + 8);
  };
  auto write = [&](int buf) {
    *(uint4*)&At[buf][arow][aq * 8] = g0r;
    *(uint4*)&At[buf][arow][aq * 8 + 8] = g1r;
  };
  auto compute = [&](int buf, int t) {
    u16x8 a0 = *(u16x8*)&At[buf][w * 32 + r_lo][q * 8];
    u16x8 a1 = *(u16x8*)&At[buf][w * 32 + 16 + r_lo][q * 8];
    #pragma unroll
    for (int ct = 0; ct < 8; ++ct) {
      u16x8 bF = *(const u16x8*)(Wcat + (size_t)(ct * 16 + r_lo) * 640 + t * 32 + q * 8);
      acc[0][ct] = mfma_bf16(a0, bF, acc[0][ct]);
      acc[1][ct] = mfma_bf16(a1, bF, acc[1][ct]);
    }
  };

  issue(0);
  write(0);
  __syncthreads();
  for (int t = 0; t < 20; ++t) {
    const int buf = t & 1;
    if (t < 19) issue(t + 1);
    compute(buf, t);
    if (t < 19) write(buf ^ 1);
    __syncthreads();
  }

  #pragma unroll
  for (int rt = 0; rt < 2; ++rt) {
    #pragma unroll
    for (int j = 0; j < 4; ++j) {
      const int rl = w * 32 + rt * 16 + q * 4 + j;
      float* orow = out + (size_t)(row0 + rl) * 128;
      #pragma unroll
      for (int ct = 0; ct < 8; ++ct) {
        const int c = ct * 16 + r_lo;
        orow[c] = acc[rt][ct][j] + bfv[c];
      }
    }
  }
}

// ---------------- launch ----------------
extern "C" void kernel_launch(void* const* d_in, const int* in_sizes, int n_in,
                              void* d_out, int out_size, void* d_ws, size_t ws_size,
                              hipStream_t stream) {
  const float* adj = (const float*)d_in[0];
  const float* X   = (const float*)d_in[1];
  const float* w0  = (const float*)d_in[2];
  const float* b0  = (const float*)d_in[3];
  const float* w1  = (const float*)d_in[4];
  const float* b1  = (const float*)d_in[5];
  const float* Wf  = (const float*)d_in[6];
  const float* bf  = (const float*)d_in[7];
  float* out = (float*)d_out;
  char* ws = (char*)d_ws;

  unsigned short* XbT  = (unsigned short*)(ws + 0);          //  2,097,152 B
  unsigned short* Wc1  = (unsigned short*)(ws + 2097152);    //    131,072
  unsigned short* Wc2  = (unsigned short*)(ws + 2228224);    //     32,768
  unsigned short* Wcat = (unsigned short*)(ws + 2260992);    //    163,840
  float*          Z0   = (float*)(ws + 2424832);             // 16,777,216
  float*          dnm  = (float*)(ws + 19202048);            //    131,072
  float*          e_b  = (float*)(ws + 19333120);            //  8,388,608
  unsigned short* h0T  = (unsigned short*)(ws + 27721728);   //  4,194,304
  unsigned short* G    = (unsigned short*)(ws + 31916032);   // 10,485,760  (end ~42.4 MB)

  hipLaunchKernelGGL(prep_weights, dim3(640), dim3(256), 0, stream, w0, w1, Wf, Wc1, Wc2, Wcat);
  hipLaunchKernelGGL(prep_x,       dim3(128), dim3(256), 0, stream, X, XbT, G);
  hipLaunchKernelGGL(pass1_kernel, dim3(16, 16), dim3(256), 0, stream, adj, X, XbT, Z0, dnm);
  hipLaunchKernelGGL(mid_kernel,   dim3(64, 4),  dim3(256), 0, stream, Z0, dnm, Wc1, Wc2, b0, b1, e_b, h0T, G);
  hipLaunchKernelGGL(pass2_kernel, dim3(16, 16), dim3(256), 0, stream, adj, h0T, e_b, dnm, G);
  hipLaunchKernelGGL(pass3_kernel, dim3(64), dim3(256), 0, stream, G, Wcat, bf, out);
}